// Round 5
// baseline (1017.519 us; speedup 1.0000x reference)
//
#include <hip/hip_runtime.h>
#include <math.h>

// Problem constants
constexpr int Bsz  = 8;
constexpr int Ntok = 1920;
constexpr int Cdim = 512;
constexpr int BLK  = 192;
constexpr int Mrows = Bsz * Ntok;      // 15360
constexpr int NBLK  = Mrows / BLK;     // 80
constexpr float SCALE = 0.02209708691207961f;  // 2048^-0.5

typedef __bf16 bf16x8 __attribute__((ext_vector_type(8)));
typedef float  f32x4  __attribute__((ext_vector_type(4)));

// LDS plane geometry: operand tile 128 rows x 32 k -> 4 planes [kg][row][8 bf16]
// plane stride 1040 shorts = 2080 B (2048 data + 32 pad -> kg planes start on
// banks 0/8/16/24). Each plane = two 1 KB chunks, gload_lds writes lane*16.
constexpr int PS = 1040;

#define GLOAD_LDS16(gp, lp) __builtin_amdgcn_global_load_lds( \
    (const __attribute__((address_space(1))) void*)(gp),      \
    (__attribute__((address_space(3))) void*)(lp), 16, 0, 0)

// ---- bf16 helpers (RNE, finite values only) ----
__device__ inline unsigned short f2bf(float f) {
    unsigned int u = __float_as_uint(f);
    unsigned int r = (u + 0x7FFFu + ((u >> 16) & 1u)) >> 16;
    return (unsigned short)r;
}
__device__ inline float bf2f(unsigned short h) {
    return __uint_as_float((unsigned int)h << 16);
}

// ---------------- token mean (two-stage) ----------------
__global__ void mean_partial(const float* __restrict__ g, float* __restrict__ part) {
    int b = blockIdx.x, t = blockIdx.y, c = threadIdx.x;
    const float* p = g + ((size_t)b * Ntok + (size_t)t * 48) * Cdim + c;
    float s = 0.f;
    #pragma unroll 4
    for (int n = 0; n < 48; ++n) s += p[(size_t)n * Cdim];
    part[((size_t)b * 40 + t) * Cdim + c] = s;
}

__global__ void mean_final(const float* __restrict__ part, float* __restrict__ meang) {
    int b = blockIdx.x, c = threadIdx.x;
    float s = 0.f;
    for (int t = 0; t < 40; ++t) s += part[((size_t)b * 40 + t) * Cdim + c];
    meang[b * Cdim + c] = s * (1.0f / (float)Ntok);
}

// ---------------- per-row inverse norm of g ----------------
__global__ void invnorm_k(const float* __restrict__ g, float* __restrict__ invn) {
    int wid = threadIdx.x >> 6, lane = threadIdx.x & 63;
    int row = blockIdx.x * 4 + wid;
    const float* p = g + (size_t)row * Cdim;
    float ss = 0.f;
    #pragma unroll
    for (int i = lane; i < Cdim; i += 64) { float v = p[i]; ss += v * v; }
    #pragma unroll
    for (int o = 1; o < 64; o <<= 1) ss += __shfl_xor(ss, o);
    if (lane == 0) {
        float n = sqrtf(ss);
        invn[row] = 1.0f / fmaxf(n, 1e-12f);
    }
}

// ---------------- f32 -> (hi,lo) bf16 split, optional per-token bias ----------------
__global__ void split_k(const float* __restrict__ src, const float* __restrict__ bias,
                        unsigned short* __restrict__ hi, unsigned short* __restrict__ lo,
                        int n4) {
    int i = blockIdx.x * 256 + threadIdx.x;
    if (i >= n4) return;
    float4 v = ((const float4*)src)[i];
    if (bias) {
        int b  = i / (Ntok * Cdim / 4);
        int c4 = (i & (Cdim / 4 - 1)) << 2;
        float4 bv = *(const float4*)&bias[b * Cdim + c4];
        v.x += bv.x; v.y += bv.y; v.z += bv.z; v.w += bv.w;
    }
    ushort4 h, l;
    h.x = f2bf(v.x); l.x = f2bf(v.x - bf2f(h.x));
    h.y = f2bf(v.y); l.y = f2bf(v.y - bf2f(h.y));
    h.z = f2bf(v.z); l.z = f2bf(v.z - bf2f(h.z));
    h.w = f2bf(v.w); l.w = f2bf(v.w - bf2f(h.w));
    ((ushort4*)hi)[i] = h;
    ((ushort4*)lo)[i] = l;
}

// ---------------- batched 64x64-tiled u16 transpose (hi+lo together) ----------------
__global__ __launch_bounds__(256) void transpose2(
    const unsigned short* __restrict__ ih, const unsigned short* __restrict__ il,
    unsigned short* __restrict__ oh, unsigned short* __restrict__ ol,
    int R, int C, long inB, long outB)
{
    int z = blockIdx.z;
    ih += (size_t)z * inB;  il += (size_t)z * inB;
    oh += (size_t)z * outB; ol += (size_t)z * outB;
    __shared__ unsigned short th[64][68], tl[64][68];
    int r0 = blockIdx.y * 64, c0 = blockIdx.x * 64;
    int tr = threadIdx.x >> 4, tc = (threadIdx.x & 15) * 4;
    for (int rr = tr; rr < 64; rr += 16) {
        ushort4 h = *(const ushort4*)&ih[(size_t)(r0 + rr) * C + c0 + tc];
        ushort4 l = *(const ushort4*)&il[(size_t)(r0 + rr) * C + c0 + tc];
        th[tc + 0][rr] = h.x; th[tc + 1][rr] = h.y; th[tc + 2][rr] = h.z; th[tc + 3][rr] = h.w;
        tl[tc + 0][rr] = l.x; tl[tc + 1][rr] = l.y; tl[tc + 2][rr] = l.z; tl[tc + 3][rr] = l.w;
    }
    __syncthreads();
    for (int cc = tr; cc < 64; cc += 16) {
        ushort4 h = *(const ushort4*)&th[cc][tc];
        ushort4 l = *(const ushort4*)&tl[cc][tc];
        *(ushort4*)&oh[(size_t)(c0 + cc) * R + r0 + tc] = h;
        *(ushort4*)&ol[(size_t)(c0 + cc) * R + r0 + tc] = l;
    }
}

// ---------------- split-bf16 MFMA GEMM (NT), global_load_lds staging ----------------
// O = alpha * rs*cs * (A · B^T); A [M,K], B [N,K] k-contiguous; A ≈ Ahi+Alo etc;
// acc = Ah·Bh + Ah·Bl + Al·Bh in f32. Wave w stages LDS buffer w (8 x 1KB chunks).
__global__ __launch_bounds__(256) void mfma_gemm(
    const unsigned short* __restrict__ Ahi, const unsigned short* __restrict__ Alo,
    const unsigned short* __restrict__ Bhi, const unsigned short* __restrict__ Blo,
    float* __restrict__ Of32, unsigned short* __restrict__ Ohi, unsigned short* __restrict__ Olo,
    int M, int N, int K,
    long aB, long bB, long oB,
    float alpha, const float* __restrict__ rs, const float* __restrict__ cs, int sB)
{
    int z = blockIdx.z;
    int m0 = blockIdx.y * 128, n0 = blockIdx.x * 128;

    __shared__ __align__(16) unsigned short As_h[4 * PS];
    __shared__ __align__(16) unsigned short As_l[4 * PS];
    __shared__ __align__(16) unsigned short Bs_h[4 * PS];
    __shared__ __align__(16) unsigned short Bs_l[4 * PS];

    int tid  = threadIdx.x;
    int lane = tid & 63, wid = tid >> 6;
    int wm = (wid >> 1) * 64, wn = (wid & 1) * 64;

    // this wave's staging assignment: one of the 4 operand buffers
    const unsigned short* src =
        (wid == 0) ? Ahi + (size_t)z * aB :
        (wid == 1) ? Alo + (size_t)z * aB :
        (wid == 2) ? Bhi + (size_t)z * bB :
                     Blo + (size_t)z * bB;
    unsigned short* dst =
        (wid == 0) ? As_h : (wid == 1) ? As_l : (wid == 2) ? Bs_h : Bs_l;
    int rc0 = (wid < 2) ? m0 : n0;
    int lim = ((wid < 2) ? M : N) - 1;

    f32x4 acc[4][4] = {};

    for (int k0 = 0; k0 < K; k0 += 32) {
        // stage this wave's 8 KB buffer as 8 x 1KB global_load_lds chunks
        #pragma unroll
        for (int c = 0; c < 8; ++c) {
            int kg = c >> 1, half = c & 1;
            int gr = min(rc0 + half * 64 + lane, lim);
            const unsigned short* gp = src + (size_t)gr * K + k0 + kg * 8;
            GLOAD_LDS16(gp, &dst[kg * PS + half * 512]);
        }
        __syncthreads();   // compiler drains vmcnt before s_barrier

        int fr = lane & 15, kg = lane >> 4;
        int pb = kg * PS + fr * 8;
        bf16x8 ah[4], al[4], bh[4], bl[4];
        #pragma unroll
        for (int f = 0; f < 4; ++f) {
            ah[f] = *(const bf16x8*)&As_h[pb + (wm + f * 16) * 8];
            al[f] = *(const bf16x8*)&As_l[pb + (wm + f * 16) * 8];
            bh[f] = *(const bf16x8*)&Bs_h[pb + (wn + f * 16) * 8];
            bl[f] = *(const bf16x8*)&Bs_l[pb + (wn + f * 16) * 8];
        }
        #pragma unroll
        for (int i = 0; i < 4; ++i)
            #pragma unroll
            for (int j = 0; j < 4; ++j) {
                acc[i][j] = __builtin_amdgcn_mfma_f32_16x16x32_bf16(ah[i], bh[j], acc[i][j], 0, 0, 0);
                acc[i][j] = __builtin_amdgcn_mfma_f32_16x16x32_bf16(ah[i], bl[j], acc[i][j], 0, 0, 0);
                acc[i][j] = __builtin_amdgcn_mfma_f32_16x16x32_bf16(al[i], bh[j], acc[i][j], 0, 0, 0);
            }
        __syncthreads();
    }

    float* O           = Of32 ? Of32 + (size_t)z * oB : nullptr;
    unsigned short* OH = Ohi ? Ohi + (size_t)z * oB : nullptr;
    unsigned short* OL = Olo ? Olo + (size_t)z * oB : nullptr;
    int fr = lane & 15, fq = lane >> 4;
    #pragma unroll
    for (int i = 0; i < 4; ++i) {
        #pragma unroll
        for (int r = 0; r < 4; ++r) {
            int gm = m0 + wm + i * 16 + fq * 4 + r;
            if (gm >= M) continue;
            float rf = alpha * (rs ? rs[(size_t)z * sB + gm] : 1.0f);
            #pragma unroll
            for (int j = 0; j < 4; ++j) {
                int gn = n0 + wn + j * 16 + fr;
                if (gn >= N) continue;
                float v = acc[i][j][r] * rf * (cs ? cs[(size_t)z * sB + gn] : 1.0f);
                size_t off = (size_t)gm * N + gn;
                if (O) O[off] = v;
                else {
                    unsigned short h = f2bf(v);
                    OH[off] = h;
                    OL[off] = f2bf(v - bf2f(h));
                }
            }
        }
    }
}

// ---------------- in-place row softmax on split-bf16 scores ----------------
__global__ __launch_bounds__(256) void softmax_inplace(
    unsigned short* __restrict__ Phi, unsigned short* __restrict__ Plo, int cols)
{
    __shared__ float buf[1920];
    __shared__ float red[4];
    size_t row = blockIdx.x;
    unsigned short* ph = Phi + row * (size_t)cols;
    unsigned short* pl = Plo + row * (size_t)cols;
    int tid = threadIdx.x;
    int nq = cols >> 2;

    float lmax = -1e30f;
    for (int q = tid; q < nq; q += 256) {
        ushort4 h = ((const ushort4*)ph)[q];
        ushort4 l = ((const ushort4*)pl)[q];
        float v0 = bf2f(h.x) + bf2f(l.x);
        float v1 = bf2f(h.y) + bf2f(l.y);
        float v2 = bf2f(h.z) + bf2f(l.z);
        float v3 = bf2f(h.w) + bf2f(l.w);
        buf[q * 4 + 0] = v0; buf[q * 4 + 1] = v1;
        buf[q * 4 + 2] = v2; buf[q * 4 + 3] = v3;
        lmax = fmaxf(lmax, fmaxf(fmaxf(v0, v1), fmaxf(v2, v3)));
    }
    #pragma unroll
    for (int o = 1; o < 64; o <<= 1) lmax = fmaxf(lmax, __shfl_xor(lmax, o));
    if ((tid & 63) == 0) red[tid >> 6] = lmax;
    __syncthreads();
    float bmax = fmaxf(fmaxf(red[0], red[1]), fmaxf(red[2], red[3]));

    float lsum = 0.f;
    for (int c = tid; c < cols; c += 256) {
        float e = expf(buf[c] - bmax);
        buf[c] = e;
        lsum += e;
    }
    #pragma unroll
    for (int o = 1; o < 64; o <<= 1) lsum += __shfl_xor(lsum, o);
    __syncthreads();
    if ((tid & 63) == 0) red[tid >> 6] = lsum;
    __syncthreads();
    float inv = 1.0f / (red[0] + red[1] + red[2] + red[3]);

    for (int q = tid; q < nq; q += 256) {
        float v0 = buf[q * 4 + 0] * inv;
        float v1 = buf[q * 4 + 1] * inv;
        float v2 = buf[q * 4 + 2] * inv;
        float v3 = buf[q * 4 + 3] * inv;
        ushort4 h, l;
        h.x = f2bf(v0); l.x = f2bf(v0 - bf2f(h.x));
        h.y = f2bf(v1); l.y = f2bf(v1 - bf2f(h.y));
        h.z = f2bf(v2); l.z = f2bf(v2 - bf2f(h.z));
        h.w = f2bf(v3); l.w = f2bf(v3 - bf2f(h.w));
        ((ushort4*)ph)[q] = h;
        ((ushort4*)pl)[q] = l;
    }
}

// ---------------- launch ----------------
extern "C" void kernel_launch(void* const* d_in, const int* in_sizes, int n_in,
                              void* d_out, int out_size, void* d_ws, size_t ws_size,
                              hipStream_t stream) {
    (void)in_sizes; (void)n_in; (void)out_size;
    const float* x  = (const float*)d_in[0];
    const float* g  = (const float*)d_in[1];
    const float* Wq = (const float*)d_in[2];
    const float* Wg = (const float*)d_in[3];
    float* out = (float*)d_out;

    const size_t GE = (size_t)Mrows * Cdim;      // 7,864,320 elems
    auto rnd = [](size_t b) { return (b + 255) & ~(size_t)255; };

    auto need = [&](int CH) -> size_t {
        size_t t = 0;
        t += rnd(Bsz * Cdim * 4) + rnd(Bsz * 40 * Cdim * 4) + rnd(Mrows * 4);
        t += 4 * rnd(GE * 2);
        t += 4 * rnd((size_t)Cdim * Cdim * 2);
        t += 6 * rnd(GE * 2);
        t += 2 * rnd(GE * 2);
        t += 2 * rnd((size_t)NBLK * BLK * BLK * 2);
        t += 2 * rnd((size_t)CH * Ntok * Ntok * 2);
        return t;
    };
    int CH = 8;
    while (CH > 1 && need(CH) > ws_size) CH >>= 1;

    char* ws = (char*)d_ws;
    size_t off = 0;
    auto alloc = [&](size_t bytes) { char* p = ws + off; off += rnd(bytes); return p; };

    float* meang = (float*)alloc(Bsz * Cdim * 4);
    float* part  = (float*)alloc(Bsz * 40 * Cdim * 4);
    float* invn  = (float*)alloc(Mrows * 4);
    unsigned short* ghi  = (unsigned short*)alloc(GE * 2);
    unsigned short* glo  = (unsigned short*)alloc(GE * 2);
    unsigned short* qhi  = (unsigned short*)alloc(GE * 2);   // reused as g2T hi after step 3
    unsigned short* qlo  = (unsigned short*)alloc(GE * 2);   // reused as g2T lo after step 3
    unsigned short* wqhi = (unsigned short*)alloc((size_t)Cdim * Cdim * 2);
    unsigned short* wqlo = (unsigned short*)alloc((size_t)Cdim * Cdim * 2);
    unsigned short* wghi = (unsigned short*)alloc((size_t)Cdim * Cdim * 2);
    unsigned short* wglo = (unsigned short*)alloc((size_t)Cdim * Cdim * 2);
    unsigned short* rqhi = (unsigned short*)alloc(GE * 2);
    unsigned short* rqlo = (unsigned short*)alloc(GE * 2);
    unsigned short* rghi = (unsigned short*)alloc(GE * 2);
    unsigned short* rglo = (unsigned short*)alloc(GE * 2);
    unsigned short* g2hi = (unsigned short*)alloc(GE * 2);
    unsigned short* g2lo = (unsigned short*)alloc(GE * 2);
    unsigned short* gThi = (unsigned short*)alloc(GE * 2);   // [NBLK][512][192]
    unsigned short* gTlo = (unsigned short*)alloc(GE * 2);
    unsigned short* sbhi = (unsigned short*)alloc((size_t)NBLK * BLK * BLK * 2);
    unsigned short* sblo = (unsigned short*)alloc((size_t)NBLK * BLK * BLK * 2);
    unsigned short* s2hi = (unsigned short*)alloc((size_t)CH * Ntok * Ntok * 2);
    unsigned short* s2lo = (unsigned short*)alloc((size_t)CH * Ntok * Ntok * 2);
    unsigned short* g2Thi = qhi;                             // [Bsz][512][1920]
    unsigned short* g2Tlo = qlo;

    // 1. token mean of g; per-row inv norms
    mean_partial<<<dim3(Bsz, 40), 512, 0, stream>>>(g, part);
    mean_final<<<Bsz, 512, 0, stream>>>(part, meang);
    invnorm_k<<<Mrows / 4, 256, 0, stream>>>(g, invn);

    // 2. hi/lo splits
    split_k<<<(int)(GE / 4 + 255) / 256, 256, 0, stream>>>(g, nullptr, ghi, glo, (int)(GE / 4));
    split_k<<<(int)(GE / 4 + 255) / 256, 256, 0, stream>>>(x, meang, qhi, qlo, (int)(GE / 4));
    split_k<<<(Cdim * Cdim / 4) / 256, 256, 0, stream>>>(Wq, nullptr, wqhi, wqlo, Cdim * Cdim / 4);
    split_k<<<(Cdim * Cdim / 4) / 256, 256, 0, stream>>>(Wg, nullptr, wghi, wglo, Cdim * Cdim / 4);

    // 2b. gT: per 192-block transpose of g  [NBLK][512][192]
    transpose2<<<dim3(Cdim / 64, BLK / 64, NBLK), 256, 0, stream>>>(
        ghi, glo, gThi, gTlo, BLK, Cdim, (long)BLK * Cdim, (long)Cdim * BLK);

    // 3. rel_q = q @ Wq^T -> split  [15360,512]   (q dead afterwards)
    mfma_gemm<<<dim3(Cdim / 128, Mrows / 128), 256, 0, stream>>>(
        qhi, qlo, wqhi, wqlo, nullptr, rqhi, rqlo,
        Mrows, Cdim, Cdim, 0, 0, 0, 1.0f, nullptr, nullptr, 0);

    // 4. block scores = (g·g^T)*invn_i*invn_j*SCALE -> split  [80][192][192]
    mfma_gemm<<<dim3(2, 2, NBLK), 256, 0, stream>>>(
        ghi, glo, ghi, glo, nullptr, sbhi, sblo,
        BLK, BLK, Cdim, (long)BLK * Cdim, (long)BLK * Cdim, (long)BLK * BLK,
        SCALE, invn, invn, BLK);

    // 5. block softmax in place
    softmax_inplace<<<NBLK * BLK, 256, 0, stream>>>(sbhi, sblo, BLK);

    // 6. g2 = attn @ gb = attn · (gT)^T -> split  [80][192][512]
    mfma_gemm<<<dim3(Cdim / 128, 2, NBLK), 256, 0, stream>>>(
        sbhi, sblo, gThi, gTlo, nullptr, g2hi, g2lo,
        BLK, Cdim, BLK, (long)BLK * BLK, (long)Cdim * BLK, (long)BLK * Cdim,
        1.0f, nullptr, nullptr, 0);

    // 6b. g2T: per-batch transpose of g2  [Bsz][512][1920]  (into dead q buffers)
    transpose2<<<dim3(Cdim / 64, Ntok / 64, Bsz), 256, 0, stream>>>(
        g2hi, g2lo, g2Thi, g2Tlo, Ntok, Cdim, (long)Ntok * Cdim, (long)Cdim * Ntok);

    // 7. rel_g = g2 @ Wg^T -> split  [15360,512]
    mfma_gemm<<<dim3(Cdim / 128, Mrows / 128), 256, 0, stream>>>(
        g2hi, g2lo, wghi, wglo, nullptr, rghi, rglo,
        Mrows, Cdim, Cdim, 0, 0, 0, 1.0f, nullptr, nullptr, 0);

    // 8. global attention, CH batches per chunk
    for (int c0 = 0; c0 < Bsz; c0 += CH) {
        size_t o2 = (size_t)c0 * Ntok * Cdim;
        // scores2 = rel_q @ rel_g^T * SCALE -> split  [CH][1920][1920]
        mfma_gemm<<<dim3(Ntok / 128, Ntok / 128, CH), 256, 0, stream>>>(
            rqhi + o2, rqlo + o2, rghi + o2, rglo + o2, nullptr, s2hi, s2lo,
            Ntok, Ntok, Cdim,
            (long)Ntok * Cdim, (long)Ntok * Cdim, (long)Ntok * Ntok,
            SCALE, nullptr, nullptr, 0);
        // softmax in place
        softmax_inplace<<<CH * Ntok, 256, 0, stream>>>(s2hi, s2lo, Ntok);
        // out = attn2 @ g2 = attn2 · (g2T)^T -> f32  [CH][1920][512]
        mfma_gemm<<<dim3(Cdim / 128, Ntok / 128, CH), 256, 0, stream>>>(
            s2hi, s2lo, g2Thi + (size_t)c0 * Cdim * Ntok, g2Tlo + (size_t)c0 * Cdim * Ntok,
            out + o2, nullptr, nullptr,
            Ntok, Cdim, Ntok,
            (long)Ntok * Ntok, (long)Cdim * Ntok, (long)Ntok * Cdim,
            1.0f, nullptr, nullptr, 0);
    }
}

// Round 6
// 571.849 us; speedup vs baseline: 1.7793x; 1.7793x over previous
//
#include <hip/hip_runtime.h>
#include <math.h>

// Problem constants
constexpr int Bsz  = 8;
constexpr int Ntok = 1920;
constexpr int Cdim = 512;
constexpr int BLK  = 192;
constexpr int Mrows = Bsz * Ntok;      // 15360
constexpr int NBLK  = Mrows / BLK;     // 80
constexpr float SCALE = 0.02209708691207961f;  // 2048^-0.5

typedef __bf16 bf16x8 __attribute__((ext_vector_type(8)));
typedef float  f32x4  __attribute__((ext_vector_type(4)));

#define GLOAD_LDS16(gp, lp) __builtin_amdgcn_global_load_lds( \
    (const __attribute__((address_space(1))) void*)(gp),      \
    (__attribute__((address_space(3))) void*)(lp), 16, 0, 0)

// chunk swizzle within a 64B row (4 x 16B chunks): spreads ds_read banks
__device__ inline int sfun(int r) { return (r & 3) ^ ((r >> 2) & 3); }

// ---- bf16 helpers (RNE, finite values only) ----
__device__ inline unsigned short f2bf(float f) {
    unsigned int u = __float_as_uint(f);
    unsigned int r = (u + 0x7FFFu + ((u >> 16) & 1u)) >> 16;
    return (unsigned short)r;
}
__device__ inline float bf2f(unsigned short h) {
    return __uint_as_float((unsigned int)h << 16);
}

// ---------------- token mean (two-stage) ----------------
__global__ void mean_partial(const float* __restrict__ g, float* __restrict__ part) {
    int b = blockIdx.x, t = blockIdx.y, c = threadIdx.x;
    const float* p = g + ((size_t)b * Ntok + (size_t)t * 48) * Cdim + c;
    float s = 0.f;
    #pragma unroll 4
    for (int n = 0; n < 48; ++n) s += p[(size_t)n * Cdim];
    part[((size_t)b * 40 + t) * Cdim + c] = s;
}

__global__ void mean_final(const float* __restrict__ part, float* __restrict__ meang) {
    int b = blockIdx.x, c = threadIdx.x;
    float s = 0.f;
    for (int t = 0; t < 40; ++t) s += part[((size_t)b * 40 + t) * Cdim + c];
    meang[b * Cdim + c] = s * (1.0f / (float)Ntok);
}

// ---------------- per-row inverse norm of g ----------------
__global__ void invnorm_k(const float* __restrict__ g, float* __restrict__ invn) {
    int wid = threadIdx.x >> 6, lane = threadIdx.x & 63;
    int row = blockIdx.x * 4 + wid;
    const float* p = g + (size_t)row * Cdim;
    float ss = 0.f;
    #pragma unroll
    for (int i = lane; i < Cdim; i += 64) { float v = p[i]; ss += v * v; }
    #pragma unroll
    for (int o = 1; o < 64; o <<= 1) ss += __shfl_xor(ss, o);
    if (lane == 0) {
        float n = sqrtf(ss);
        invn[row] = 1.0f / fmaxf(n, 1e-12f);
    }
}

// ---------------- f32 -> (hi,lo) bf16 split, optional per-token bias ----------------
__global__ void split_k(const float* __restrict__ src, const float* __restrict__ bias,
                        unsigned short* __restrict__ hi, unsigned short* __restrict__ lo,
                        int n4) {
    int i = blockIdx.x * 256 + threadIdx.x;
    if (i >= n4) return;
    float4 v = ((const float4*)src)[i];
    if (bias) {
        int b  = i / (Ntok * Cdim / 4);
        int c4 = (i & (Cdim / 4 - 1)) << 2;
        float4 bv = *(const float4*)&bias[b * Cdim + c4];
        v.x += bv.x; v.y += bv.y; v.z += bv.z; v.w += bv.w;
    }
    ushort4 h, l;
    h.x = f2bf(v.x); l.x = f2bf(v.x - bf2f(h.x));
    h.y = f2bf(v.y); l.y = f2bf(v.y - bf2f(h.y));
    h.z = f2bf(v.z); l.z = f2bf(v.z - bf2f(h.z));
    h.w = f2bf(v.w); l.w = f2bf(v.w - bf2f(h.w));
    ((ushort4*)hi)[i] = h;
    ((ushort4*)lo)[i] = l;
}

// ---------------- batched 64x64-tiled u16 transpose (hi+lo together) ----------------
__global__ __launch_bounds__(256) void transpose2(
    const unsigned short* __restrict__ ih, const unsigned short* __restrict__ il,
    unsigned short* __restrict__ oh, unsigned short* __restrict__ ol,
    int R, int C, long inB, long outB)
{
    int z = blockIdx.z;
    ih += (size_t)z * inB;  il += (size_t)z * inB;
    oh += (size_t)z * outB; ol += (size_t)z * outB;
    __shared__ unsigned short th[64][68], tl[64][68];
    int r0 = blockIdx.y * 64, c0 = blockIdx.x * 64;
    int tr = threadIdx.x >> 4, tc = (threadIdx.x & 15) * 4;
    for (int rr = tr; rr < 64; rr += 16) {
        ushort4 h = *(const ushort4*)&ih[(size_t)(r0 + rr) * C + c0 + tc];
        ushort4 l = *(const ushort4*)&il[(size_t)(r0 + rr) * C + c0 + tc];
        th[tc + 0][rr] = h.x; th[tc + 1][rr] = h.y; th[tc + 2][rr] = h.z; th[tc + 3][rr] = h.w;
        tl[tc + 0][rr] = l.x; tl[tc + 1][rr] = l.y; tl[tc + 2][rr] = l.z; tl[tc + 3][rr] = l.w;
    }
    __syncthreads();
    for (int cc = tr; cc < 64; cc += 16) {
        ushort4 h = *(const ushort4*)&th[cc][tc];
        ushort4 l = *(const ushort4*)&tl[cc][tc];
        *(ushort4*)&oh[(size_t)(c0 + cc) * R + r0 + tc] = h;
        *(ushort4*)&ol[(size_t)(c0 + cc) * R + r0 + tc] = l;
    }
}

// ---------------- split-bf16 MFMA GEMM (NT), coalesced gload_lds + XOR swizzle ----
// O = alpha * rs*cs * (A · B^T); A [M,ld], B [N,ld] k-contiguous; A ≈ Ahi+Alo etc;
// acc = Ah·Bh + Ah·Bl + Al·Bh (f32). Tile: BM=FM*32 rows x BN=FN*32 cols, 4 waves
// as 2x2 of (FM*16 x FN*16). Optional split-K: blockIdx.z = z*kSplit + half,
// K-slice = [half*KS, (half+1)*KS), f32 partial at half*oHalf + z*oB.
template<int FM, int FN>
__global__ __launch_bounds__(256) void mfma_gemm(
    const unsigned short* __restrict__ Ahi, const unsigned short* __restrict__ Alo,
    const unsigned short* __restrict__ Bhi, const unsigned short* __restrict__ Blo,
    float* __restrict__ Of32, unsigned short* __restrict__ Ohi, unsigned short* __restrict__ Olo,
    int M, int N, int KS, int ld, int kSplit,
    long aB, long bB, long oB, long oHalf,
    float alpha, const float* __restrict__ rs, const float* __restrict__ cs, int sB)
{
    constexpr int BM = FM * 32, BN = FN * 32;
    int zz = blockIdx.z;
    int z = zz / kSplit, half = zz % kSplit;
    int koff = half * KS;

    int m0 = blockIdx.y * BM, n0 = blockIdx.x * BN;

    __shared__ __align__(16) unsigned short As_h[BM * 32];
    __shared__ __align__(16) unsigned short As_l[BM * 32];
    __shared__ __align__(16) unsigned short Bs_h[BN * 32];
    __shared__ __align__(16) unsigned short Bs_l[BN * 32];

    int tid  = threadIdx.x;
    int lane = tid & 63, wid = tid >> 6;
    int wm = (wid >> 1) * (FM * 16), wn = (wid & 1) * (FN * 16);

    // staging assignment: wave w owns one operand buffer
    const unsigned short* src =
        (wid == 0) ? Ahi + (size_t)z * aB :
        (wid == 1) ? Alo + (size_t)z * aB :
        (wid == 2) ? Bhi + (size_t)z * bB :
                     Blo + (size_t)z * bB;
    unsigned short* dst =
        (wid == 0) ? As_h : (wid == 1) ? As_l : (wid == 2) ? Bs_h : Bs_l;
    constexpr int RA = BM, RB = BN;
    int rows = (wid < 2) ? RA : RB;
    int rc0  = (wid < 2) ? m0 : n0;
    // per-lane fixed parts of the staging address
    int srow = lane >> 2;                      // row within 16-row chunk
    int sgc  = (lane & 3) ^ sfun(srow);        // swizzled global chunk
    src += (size_t)(rc0 + srow) * ld + sgc * 8 + koff;

    f32x4 acc[FM][FN] = {};

    for (int k0 = 0; k0 < KS; k0 += 32) {
        // stage: rows/16 chunks of 1KB; chunk h covers rows h*16..h*16+15
        #pragma unroll
        for (int h = 0; h < ((RA > RB ? RA : RB) / 16); ++h) {
            if (h < rows / 16)
                GLOAD_LDS16(src + (size_t)h * 16 * ld + k0, dst + h * 512);
        }
        __syncthreads();

        int fr = lane & 15, kg = lane >> 4;
        bf16x8 ah[FM], al[FM], bh[FN], bl[FN];
        #pragma unroll
        for (int f = 0; f < FM; ++f) {
            int r = wm + f * 16 + fr;
            int ad = r * 32 + ((kg ^ sfun(r)) << 3);
            ah[f] = *(const bf16x8*)&As_h[ad];
            al[f] = *(const bf16x8*)&As_l[ad];
        }
        #pragma unroll
        for (int f = 0; f < FN; ++f) {
            int r = wn + f * 16 + fr;
            int ad = r * 32 + ((kg ^ sfun(r)) << 3);
            bh[f] = *(const bf16x8*)&Bs_h[ad];
            bl[f] = *(const bf16x8*)&Bs_l[ad];
        }
        #pragma unroll
        for (int i = 0; i < FM; ++i)
            #pragma unroll
            for (int j = 0; j < FN; ++j) {
                acc[i][j] = __builtin_amdgcn_mfma_f32_16x16x32_bf16(ah[i], bh[j], acc[i][j], 0, 0, 0);
                acc[i][j] = __builtin_amdgcn_mfma_f32_16x16x32_bf16(ah[i], bl[j], acc[i][j], 0, 0, 0);
                acc[i][j] = __builtin_amdgcn_mfma_f32_16x16x32_bf16(al[i], bh[j], acc[i][j], 0, 0, 0);
            }
        __syncthreads();
    }

    float* O           = Of32 ? Of32 + (size_t)half * oHalf + (size_t)z * oB : nullptr;
    unsigned short* OH = Ohi ? Ohi + (size_t)z * oB : nullptr;
    unsigned short* OL = Olo ? Olo + (size_t)z * oB : nullptr;
    int fr = lane & 15, fq = lane >> 4;
    #pragma unroll
    for (int i = 0; i < FM; ++i) {
        #pragma unroll
        for (int r = 0; r < 4; ++r) {
            int gm = m0 + wm + i * 16 + fq * 4 + r;
            float rf = alpha * (rs ? rs[(size_t)z * sB + gm] : 1.0f);
            #pragma unroll
            for (int j = 0; j < FN; ++j) {
                int gn = n0 + wn + j * 16 + fr;
                float v = acc[i][j][r] * rf * (cs ? cs[(size_t)z * sB + gn] : 1.0f);
                size_t off = (size_t)gm * N + gn;
                if (O) O[off] = v;
                else {
                    unsigned short h = f2bf(v);
                    OH[off] = h;
                    OL[off] = f2bf(v - bf2f(h));
                }
            }
        }
    }
}

// ---------------- split-K partial reduction: out = sum of 4 halves ----------------
__global__ void reduce4(const float* __restrict__ p, float* __restrict__ o,
                        int n4, long hs4) {
    int i = blockIdx.x * 256 + threadIdx.x;
    if (i >= n4) return;
    const float4* P = (const float4*)p;
    float4 a = P[i], b = P[i + hs4], c = P[i + 2 * hs4], d = P[i + 3 * hs4];
    float4 r;
    r.x = (a.x + b.x) + (c.x + d.x);
    r.y = (a.y + b.y) + (c.y + d.y);
    r.z = (a.z + b.z) + (c.z + d.z);
    r.w = (a.w + b.w) + (c.w + d.w);
    ((float4*)o)[i] = r;
}

// ---------------- in-place row softmax on split-bf16 scores ----------------
__global__ __launch_bounds__(256) void softmax_inplace(
    unsigned short* __restrict__ Phi, unsigned short* __restrict__ Plo, int cols)
{
    __shared__ float buf[1920];
    __shared__ float red[4];
    size_t row = blockIdx.x;
    unsigned short* ph = Phi + row * (size_t)cols;
    unsigned short* pl = Plo + row * (size_t)cols;
    int tid = threadIdx.x;
    int nq = cols >> 2;

    float lmax = -1e30f;
    for (int q = tid; q < nq; q += 256) {
        ushort4 h = ((const ushort4*)ph)[q];
        ushort4 l = ((const ushort4*)pl)[q];
        float v0 = bf2f(h.x) + bf2f(l.x);
        float v1 = bf2f(h.y) + bf2f(l.y);
        float v2 = bf2f(h.z) + bf2f(l.z);
        float v3 = bf2f(h.w) + bf2f(l.w);
        buf[q * 4 + 0] = v0; buf[q * 4 + 1] = v1;
        buf[q * 4 + 2] = v2; buf[q * 4 + 3] = v3;
        lmax = fmaxf(lmax, fmaxf(fmaxf(v0, v1), fmaxf(v2, v3)));
    }
    #pragma unroll
    for (int o = 1; o < 64; o <<= 1) lmax = fmaxf(lmax, __shfl_xor(lmax, o));
    if ((tid & 63) == 0) red[tid >> 6] = lmax;
    __syncthreads();
    float bmax = fmaxf(fmaxf(red[0], red[1]), fmaxf(red[2], red[3]));

    float lsum = 0.f;
    for (int c = tid; c < cols; c += 256) {
        float e = expf(buf[c] - bmax);
        buf[c] = e;
        lsum += e;
    }
    #pragma unroll
    for (int o = 1; o < 64; o <<= 1) lsum += __shfl_xor(lsum, o);
    __syncthreads();
    if ((tid & 63) == 0) red[tid >> 6] = lsum;
    __syncthreads();
    float inv = 1.0f / (red[0] + red[1] + red[2] + red[3]);

    for (int q = tid; q < nq; q += 256) {
        float v0 = buf[q * 4 + 0] * inv;
        float v1 = buf[q * 4 + 1] * inv;
        float v2 = buf[q * 4 + 2] * inv;
        float v3 = buf[q * 4 + 3] * inv;
        ushort4 h, l;
        h.x = f2bf(v0); l.x = f2bf(v0 - bf2f(h.x));
        h.y = f2bf(v1); l.y = f2bf(v1 - bf2f(h.y));
        h.z = f2bf(v2); l.z = f2bf(v2 - bf2f(h.z));
        h.w = f2bf(v3); l.w = f2bf(v3 - bf2f(h.w));
        ((ushort4*)ph)[q] = h;
        ((ushort4*)pl)[q] = l;
    }
}

// ---------------- launch ----------------
extern "C" void kernel_launch(void* const* d_in, const int* in_sizes, int n_in,
                              void* d_out, int out_size, void* d_ws, size_t ws_size,
                              hipStream_t stream) {
    (void)in_sizes; (void)n_in; (void)out_size;
    const float* x  = (const float*)d_in[0];
    const float* g  = (const float*)d_in[1];
    const float* Wq = (const float*)d_in[2];
    const float* Wg = (const float*)d_in[3];
    float* out = (float*)d_out;

    const size_t GE = (size_t)Mrows * Cdim;      // 7,864,320 elems
    auto rnd = [](size_t b) { return (b + 255) & ~(size_t)255; };

    auto need = [&](int CH) -> size_t {
        size_t t = 0;
        t += rnd(Bsz * Cdim * 4) + rnd(Bsz * 40 * Cdim * 4) + rnd(Mrows * 4);
        t += 4 * rnd(GE * 2);                        // g, gT
        t += 2 * rnd(GE * 2);                        // q (=g2T)
        t += 4 * rnd((size_t)Cdim * Cdim * 2);       // weights
        t += 6 * rnd(GE * 2);                        // rq rg g2
        t += 2 * rnd((size_t)NBLK * BLK * BLK * 2);  // block scores
        t += 2 * rnd((size_t)CH * Ntok * Ntok * 2);  // global scores
        return t;
    };
    int CH = 8;
    while (CH > 1 && need(CH) > ws_size) CH >>= 1;
    if (CH > 4) CH = 4;   // 4 is enough for full grids; keeps ws small

    char* ws = (char*)d_ws;
    size_t off = 0;
    auto alloc = [&](size_t bytes) { char* p = ws + off; off += rnd(bytes); return p; };

    float* meang = (float*)alloc(Bsz * Cdim * 4);
    float* part  = (float*)alloc(Bsz * 40 * Cdim * 4);
    float* invn  = (float*)alloc(Mrows * 4);
    // g / gT block: dead by step 8 -> reused as split-K partial (needs 4*CH*1920*512*4 B)
    unsigned short* ghi  = (unsigned short*)alloc(GE * 2);
    unsigned short* glo  = (unsigned short*)alloc(GE * 2);
    unsigned short* gThi = (unsigned short*)alloc(GE * 2);   // [NBLK][512][192]
    unsigned short* gTlo = (unsigned short*)alloc(GE * 2);
    float* partial = (float*)ghi;                            // [4][CH][1920][512] f32
    unsigned short* qhi  = (unsigned short*)alloc(GE * 2);   // reused as g2T hi after step 3
    unsigned short* qlo  = (unsigned short*)alloc(GE * 2);   // reused as g2T lo after step 3
    unsigned short* wqhi = (unsigned short*)alloc((size_t)Cdim * Cdim * 2);
    unsigned short* wqlo = (unsigned short*)alloc((size_t)Cdim * Cdim * 2);
    unsigned short* wghi = (unsigned short*)alloc((size_t)Cdim * Cdim * 2);
    unsigned short* wglo = (unsigned short*)alloc((size_t)Cdim * Cdim * 2);
    unsigned short* rqhi = (unsigned short*)alloc(GE * 2);
    unsigned short* rqlo = (unsigned short*)alloc(GE * 2);
    unsigned short* rghi = (unsigned short*)alloc(GE * 2);
    unsigned short* rglo = (unsigned short*)alloc(GE * 2);
    unsigned short* g2hi = (unsigned short*)alloc(GE * 2);
    unsigned short* g2lo = (unsigned short*)alloc(GE * 2);
    unsigned short* sbhi = (unsigned short*)alloc((size_t)NBLK * BLK * BLK * 2);
    unsigned short* sblo = (unsigned short*)alloc((size_t)NBLK * BLK * BLK * 2);
    unsigned short* s2hi = (unsigned short*)alloc((size_t)CH * Ntok * Ntok * 2);
    unsigned short* s2lo = (unsigned short*)alloc((size_t)CH * Ntok * Ntok * 2);
    unsigned short* g2Thi = qhi;                             // [Bsz][512][1920]
    unsigned short* g2Tlo = qlo;

    // 1. token mean of g; per-row inv norms
    mean_partial<<<dim3(Bsz, 40), 512, 0, stream>>>(g, part);
    mean_final<<<Bsz, 512, 0, stream>>>(part, meang);
    invnorm_k<<<Mrows / 4, 256, 0, stream>>>(g, invn);

    // 2. hi/lo splits
    split_k<<<(int)(GE / 4 + 255) / 256, 256, 0, stream>>>(g, nullptr, ghi, glo, (int)(GE / 4));
    split_k<<<(int)(GE / 4 + 255) / 256, 256, 0, stream>>>(x, meang, qhi, qlo, (int)(GE / 4));
    split_k<<<(Cdim * Cdim / 4) / 256, 256, 0, stream>>>(Wq, nullptr, wqhi, wqlo, Cdim * Cdim / 4);
    split_k<<<(Cdim * Cdim / 4) / 256, 256, 0, stream>>>(Wg, nullptr, wghi, wglo, Cdim * Cdim / 4);

    // 2b. gT: per 192-block transpose of g  [NBLK][512][192]
    transpose2<<<dim3(Cdim / 64, BLK / 64, NBLK), 256, 0, stream>>>(
        ghi, glo, gThi, gTlo, BLK, Cdim, (long)BLK * Cdim, (long)Cdim * BLK);

    // 3. rel_q = q @ Wq^T -> split  [15360,512]  (64x128 tiles, 960 blocks)
    mfma_gemm<2, 4><<<dim3(Cdim / 128, Mrows / 64), 256, 0, stream>>>(
        qhi, qlo, wqhi, wqlo, nullptr, rqhi, rqlo,
        Mrows, Cdim, Cdim, Cdim, 1, 0, 0, 0, 0, 1.0f, nullptr, nullptr, 0);

    // 4. block scores -> split  [80][192][192]  (64x64 tiles, 720 blocks)
    mfma_gemm<2, 2><<<dim3(3, 3, NBLK), 256, 0, stream>>>(
        ghi, glo, ghi, glo, nullptr, sbhi, sblo,
        BLK, BLK, Cdim, Cdim, 1,
        (long)BLK * Cdim, (long)BLK * Cdim, (long)BLK * BLK, 0,
        SCALE, invn, invn, BLK);

    // 5. block softmax in place
    softmax_inplace<<<NBLK * BLK, 256, 0, stream>>>(sbhi, sblo, BLK);

    // 6. g2 = attn · (gT)^T -> split  [80][192][512]  (64x128 tiles, 960 blocks)
    mfma_gemm<2, 4><<<dim3(Cdim / 128, 3, NBLK), 256, 0, stream>>>(
        sbhi, sblo, gThi, gTlo, nullptr, g2hi, g2lo,
        BLK, Cdim, BLK, BLK, 1,
        (long)BLK * BLK, (long)Cdim * BLK, (long)BLK * Cdim, 0,
        1.0f, nullptr, nullptr, 0);

    // 6b. g2T: per-batch transpose of g2  [Bsz][512][1920]  (into dead q buffers)
    transpose2<<<dim3(Cdim / 64, Ntok / 64, Bsz), 256, 0, stream>>>(
        g2hi, g2lo, g2Thi, g2Tlo, Ntok, Cdim, (long)Ntok * Cdim, (long)Cdim * Ntok);

    // 7. rel_g = g2 @ Wg^T -> split  [15360,512]  (64x128 tiles, 960 blocks)
    mfma_gemm<2, 4><<<dim3(Cdim / 128, Mrows / 64), 256, 0, stream>>>(
        g2hi, g2lo, wghi, wglo, nullptr, rghi, rglo,
        Mrows, Cdim, Cdim, Cdim, 1, 0, 0, 0, 0, 1.0f, nullptr, nullptr, 0);

    // 8. global attention, CH batches per chunk
    const long oHalf = (long)CH * Ntok * Cdim;    // split-K partial half-stride
    for (int c0 = 0; c0 < Bsz; c0 += CH) {
        size_t o2 = (size_t)c0 * Ntok * Cdim;
        // scores2 -> split  [CH][1920][1920]  (128x128 tiles, 225*CH blocks)
        mfma_gemm<4, 4><<<dim3(Ntok / 128, Ntok / 128, CH), 256, 0, stream>>>(
            rqhi + o2, rqlo + o2, rghi + o2, rglo + o2, nullptr, s2hi, s2lo,
            Ntok, Ntok, Cdim, Cdim, 1,
            (long)Ntok * Cdim, (long)Ntok * Cdim, (long)Ntok * Ntok, 0,
            SCALE, nullptr, nullptr, 0);
        // softmax in place
        softmax_inplace<<<CH * Ntok, 256, 0, stream>>>(s2hi, s2lo, Ntok);
        // out-partial = attn2 · (g2T)^T, split-K=4  (128x128 tiles, 240*CH blocks)
        mfma_gemm<4, 4><<<dim3(Cdim / 128, Ntok / 128, CH * 4), 256, 0, stream>>>(
            s2hi, s2lo, g2Thi + (size_t)c0 * Cdim * Ntok, g2Tlo + (size_t)c0 * Cdim * Ntok,
            partial, nullptr, nullptr,
            Ntok, Cdim, Ntok / 4, Ntok, 4,
            (long)Ntok * Ntok, (long)Cdim * Ntok, (long)Ntok * Cdim, oHalf,
            1.0f, nullptr, nullptr, 0);
        // reduce 4 partials -> out
        int n4 = (int)(oHalf / 4);
        reduce4<<<(n4 + 255) / 256, 256, 0, stream>>>(partial, out + o2, n4, oHalf / 4);
    }
}

// Round 7
// 304.675 us; speedup vs baseline: 3.3397x; 1.8769x over previous
//
#include <hip/hip_runtime.h>
#include <math.h>

// Problem constants
constexpr int Bsz  = 8;
constexpr int Ntok = 1920;
constexpr int Cdim = 512;
constexpr int BLK  = 192;
constexpr int Mrows = Bsz * Ntok;      // 15360
constexpr int NBLK  = Mrows / BLK;     // 80
constexpr float SCALE = 0.02209708691207961f;  // 2048^-0.5

typedef _Float16 half8 __attribute__((ext_vector_type(8)));
typedef float    f32x4 __attribute__((ext_vector_type(4)));

#define GLOAD_LDS16(gp, lp) __builtin_amdgcn_global_load_lds( \
    (const __attribute__((address_space(1))) void*)(gp),      \
    (__attribute__((address_space(3))) void*)(lp), 16, 0, 0)

// chunk swizzle within a 64B row (4 x 16B chunks): applied on BOTH the global
// source chunk (staging) and the ds_read chunk -> involution, banks spread.
__device__ inline int sfun(int r) { return (r & 3) ^ ((r >> 2) & 3); }

// ---- f16 helpers (HW RNE via v_cvt) ----
__device__ inline unsigned short f2h(float f) {
    _Float16 h = (_Float16)f;
    return __builtin_bit_cast(unsigned short, h);
}
__device__ inline float h2f(unsigned short u) {
    return (float)__builtin_bit_cast(_Float16, u);
}

// ---------------- token mean (two-stage) ----------------
__global__ void mean_partial(const float* __restrict__ g, float* __restrict__ part) {
    int b = blockIdx.x, t = blockIdx.y, c = threadIdx.x;
    const float* p = g + ((size_t)b * Ntok + (size_t)t * 48) * Cdim + c;
    float s = 0.f;
    #pragma unroll 4
    for (int n = 0; n < 48; ++n) s += p[(size_t)n * Cdim];
    part[((size_t)b * 40 + t) * Cdim + c] = s;
}

__global__ void mean_final(const float* __restrict__ part, float* __restrict__ meang) {
    int b = blockIdx.x, c = threadIdx.x;
    float s = 0.f;
    for (int t = 0; t < 40; ++t) s += part[((size_t)b * 40 + t) * Cdim + c];
    meang[b * Cdim + c] = s * (1.0f / (float)Ntok);
}

// ---------------- per-row inverse norm of g (f32 source) ----------------
__global__ void invnorm_k(const float* __restrict__ g, float* __restrict__ invn) {
    int wid = threadIdx.x >> 6, lane = threadIdx.x & 63;
    int row = blockIdx.x * 4 + wid;
    const float* p = g + (size_t)row * Cdim;
    float ss = 0.f;
    #pragma unroll
    for (int i = lane; i < Cdim; i += 64) { float v = p[i]; ss += v * v; }
    #pragma unroll
    for (int o = 1; o < 64; o <<= 1) ss += __shfl_xor(ss, o);
    if (lane == 0) {
        float n = sqrtf(ss);
        invn[row] = 1.0f / fmaxf(n, 1e-12f);
    }
}

// ---------------- f32 -> f16 convert, optional per-token bias ----------------
__global__ void cvt_k(const float* __restrict__ src, const float* __restrict__ bias,
                      unsigned short* __restrict__ dst, int n4) {
    int i = blockIdx.x * 256 + threadIdx.x;
    if (i >= n4) return;
    float4 v = ((const float4*)src)[i];
    if (bias) {
        int b  = i / (Ntok * Cdim / 4);
        int c4 = (i & (Cdim / 4 - 1)) << 2;
        float4 bv = *(const float4*)&bias[b * Cdim + c4];
        v.x += bv.x; v.y += bv.y; v.z += bv.z; v.w += bv.w;
    }
    ushort4 h;
    h.x = f2h(v.x); h.y = f2h(v.y); h.z = f2h(v.z); h.w = f2h(v.w);
    ((ushort4*)dst)[i] = h;
}

// ---------------- batched 64x64-tiled u16 transpose ----------------
__global__ __launch_bounds__(256) void transpose1(
    const unsigned short* __restrict__ in, unsigned short* __restrict__ out,
    int R, int C, long inB, long outB)
{
    int z = blockIdx.z;
    in  += (size_t)z * inB;
    out += (size_t)z * outB;
    __shared__ unsigned short th[64][68];
    int r0 = blockIdx.y * 64, c0 = blockIdx.x * 64;
    int tr = threadIdx.x >> 4, tc = (threadIdx.x & 15) * 4;
    for (int rr = tr; rr < 64; rr += 16) {
        ushort4 h = *(const ushort4*)&in[(size_t)(r0 + rr) * C + c0 + tc];
        th[tc + 0][rr] = h.x; th[tc + 1][rr] = h.y; th[tc + 2][rr] = h.z; th[tc + 3][rr] = h.w;
    }
    __syncthreads();
    for (int cc = tr; cc < 64; cc += 16) {
        ushort4 h = *(const ushort4*)&th[cc][tc];
        *(ushort4*)&out[(size_t)(c0 + cc) * R + r0 + tc] = h;
    }
}

// ---------------- f16 MFMA GEMM (NT), coalesced gload_lds + XOR swizzle ----------
// O = alpha * rs*cs * (A · B^T); A [M,ld], B [N,ld] k-contiguous f16;
// f32 accumulate via mfma_f32_16x16x32_f16. Tile BM=FM*32 x BN=FN*32, 4 waves
// as 2x2 of (FM*16 x FN*16). Output f32 (Of32) or f16 (Oh). Batched over z.
// All dims must divide the tile (they do for this problem).
template<int FM, int FN>
__global__ __launch_bounds__(256) void mfma_gemm(
    const unsigned short* __restrict__ A, const unsigned short* __restrict__ B,
    float* __restrict__ Of32, unsigned short* __restrict__ Oh,
    int N, int K, int ld,
    long aB, long bB, long oB,
    float alpha, const float* __restrict__ rs, const float* __restrict__ cs, int sB)
{
    constexpr int BM = FM * 32, BN = FN * 32;
    constexpr int NCH = (BM + BN) / 16;   // 1KB staging chunks per K-step
    constexpr int CPW = NCH / 4;          // chunks per wave
    int z = blockIdx.z;
    int m0 = blockIdx.y * BM, n0 = blockIdx.x * BN;

    __shared__ __align__(16) unsigned short As[BM * 32];
    __shared__ __align__(16) unsigned short Bs[BN * 32];

    int tid  = threadIdx.x;
    int lane = tid & 63, wid = tid >> 6;
    int wm = (wid >> 1) * (FM * 16), wn = (wid & 1) * (FN * 16);

    // staging: lane -> (row = lane>>2 within 16-row chunk, swizzled 16B slot)
    int srow = lane >> 2;
    int sgc  = (lane & 3) ^ sfun(srow);

    const unsigned short* csrc[CPW];
    unsigned short*       cdst[CPW];
    #pragma unroll
    for (int i = 0; i < CPW; ++i) {
        int c = wid * CPW + i;                 // wave-uniform
        if (c < BM / 16) {
            csrc[i] = A + (size_t)z * aB + (size_t)(m0 + c * 16 + srow) * ld + sgc * 8;
            cdst[i] = &As[c * 512];
        } else {
            int cb = c - BM / 16;
            csrc[i] = B + (size_t)z * bB + (size_t)(n0 + cb * 16 + srow) * ld + sgc * 8;
            cdst[i] = &Bs[cb * 512];
        }
    }

    f32x4 acc[FM][FN] = {};

    for (int k0 = 0; k0 < K; k0 += 32) {
        #pragma unroll
        for (int i = 0; i < CPW; ++i)
            GLOAD_LDS16(csrc[i] + k0, cdst[i]);
        __syncthreads();

        int fr = lane & 15, kg = lane >> 4;
        half8 a[FM], b[FN];
        #pragma unroll
        for (int f = 0; f < FM; ++f) {
            int r = wm + f * 16 + fr;
            a[f] = *(const half8*)&As[r * 32 + ((kg ^ sfun(r)) << 3)];
        }
        #pragma unroll
        for (int f = 0; f < FN; ++f) {
            int r = wn + f * 16 + fr;
            b[f] = *(const half8*)&Bs[r * 32 + ((kg ^ sfun(r)) << 3)];
        }
        #pragma unroll
        for (int i = 0; i < FM; ++i)
            #pragma unroll
            for (int j = 0; j < FN; ++j)
                acc[i][j] = __builtin_amdgcn_mfma_f32_16x16x32_f16(a[i], b[j], acc[i][j], 0, 0, 0);
        __syncthreads();
    }

    float* O          = Of32 ? Of32 + (size_t)z * oB : nullptr;
    unsigned short* H = Oh   ? Oh   + (size_t)z * oB : nullptr;
    int fr = lane & 15, fq = lane >> 4;
    #pragma unroll
    for (int i = 0; i < FM; ++i) {
        #pragma unroll
        for (int r = 0; r < 4; ++r) {
            int gm = m0 + wm + i * 16 + fq * 4 + r;
            float rf = alpha * (rs ? rs[(size_t)z * sB + gm] : 1.0f);
            #pragma unroll
            for (int j = 0; j < FN; ++j) {
                int gn = n0 + wn + j * 16 + fr;
                float v = acc[i][j][r] * rf * (cs ? cs[(size_t)z * sB + gn] : 1.0f);
                size_t off = (size_t)gm * N + gn;
                if (O) O[off] = v;
                else   H[off] = f2h(v);
            }
        }
    }
}

// ---------------- in-place row softmax on f16 scores ----------------
__global__ __launch_bounds__(256) void softmax_h(unsigned short* __restrict__ P, int cols) {
    __shared__ float buf[1920];
    __shared__ float red[4];
    size_t row = blockIdx.x;
    unsigned short* p = P + row * (size_t)cols;
    int tid = threadIdx.x;
    int nq = cols >> 2;

    float lmax = -1e30f;
    for (int q = tid; q < nq; q += 256) {
        ushort4 h = ((const ushort4*)p)[q];
        float v0 = h2f(h.x), v1 = h2f(h.y), v2 = h2f(h.z), v3 = h2f(h.w);
        buf[q * 4 + 0] = v0; buf[q * 4 + 1] = v1;
        buf[q * 4 + 2] = v2; buf[q * 4 + 3] = v3;
        lmax = fmaxf(lmax, fmaxf(fmaxf(v0, v1), fmaxf(v2, v3)));
    }
    #pragma unroll
    for (int o = 1; o < 64; o <<= 1) lmax = fmaxf(lmax, __shfl_xor(lmax, o));
    if ((tid & 63) == 0) red[tid >> 6] = lmax;
    __syncthreads();
    float bmax = fmaxf(fmaxf(red[0], red[1]), fmaxf(red[2], red[3]));

    float lsum = 0.f;
    for (int c = tid; c < cols; c += 256) {
        float e = expf(buf[c] - bmax);
        buf[c] = e;
        lsum += e;
    }
    #pragma unroll
    for (int o = 1; o < 64; o <<= 1) lsum += __shfl_xor(lsum, o);
    __syncthreads();
    if ((tid & 63) == 0) red[tid >> 6] = lsum;
    __syncthreads();
    float inv = 1.0f / (red[0] + red[1] + red[2] + red[3]);

    for (int q = tid; q < nq; q += 256) {
        ushort4 h;
        h.x = f2h(buf[q * 4 + 0] * inv);
        h.y = f2h(buf[q * 4 + 1] * inv);
        h.z = f2h(buf[q * 4 + 2] * inv);
        h.w = f2h(buf[q * 4 + 3] * inv);
        ((ushort4*)p)[q] = h;
    }
}

// ---------------- launch ----------------
extern "C" void kernel_launch(void* const* d_in, const int* in_sizes, int n_in,
                              void* d_out, int out_size, void* d_ws, size_t ws_size,
                              hipStream_t stream) {
    (void)in_sizes; (void)n_in; (void)out_size; (void)ws_size;
    const float* x  = (const float*)d_in[0];
    const float* g  = (const float*)d_in[1];
    const float* Wq = (const float*)d_in[2];
    const float* Wg = (const float*)d_in[3];
    float* out = (float*)d_out;

    const size_t GE = (size_t)Mrows * Cdim;      // 7,864,320 elems
    char* ws = (char*)d_ws;
    size_t off = 0;
    auto alloc = [&](size_t bytes) { char* p = ws + off; off += (bytes + 255) & ~(size_t)255; return p; };

    float* meang = (float*)alloc(Bsz * Cdim * 4);
    float* part  = (float*)alloc(Bsz * 40 * Cdim * 4);
    float* invn  = (float*)alloc(Mrows * 4);
    unsigned short* gh   = (unsigned short*)alloc(GE * 2);            // g f16
    unsigned short* gTh  = (unsigned short*)alloc(GE * 2);            // [NBLK][512][192]
    unsigned short* qh   = (unsigned short*)alloc(GE * 2);            // q f16; reused as g2T
    unsigned short* wqh  = (unsigned short*)alloc((size_t)Cdim * Cdim * 2);
    unsigned short* wgh  = (unsigned short*)alloc((size_t)Cdim * Cdim * 2);
    unsigned short* rqh  = (unsigned short*)alloc(GE * 2);
    unsigned short* rgh  = (unsigned short*)alloc(GE * 2);
    unsigned short* g2h  = (unsigned short*)alloc(GE * 2);
    unsigned short* sbh  = (unsigned short*)alloc((size_t)NBLK * BLK * BLK * 2);
    unsigned short* s2h  = (unsigned short*)alloc((size_t)Bsz * Ntok * Ntok * 2);  // 59 MB
    unsigned short* g2Th = qh;                                        // [Bsz][512][1920]

    // 1. token mean; per-row inv norms (f32 sources)
    mean_partial<<<dim3(Bsz, 40), 512, 0, stream>>>(g, part);
    mean_final<<<Bsz, 512, 0, stream>>>(part, meang);
    invnorm_k<<<Mrows / 4, 256, 0, stream>>>(g, invn);

    // 2. f16 conversions
    cvt_k<<<(int)(GE / 4 + 255) / 256, 256, 0, stream>>>(g, nullptr, gh, (int)(GE / 4));
    cvt_k<<<(int)(GE / 4 + 255) / 256, 256, 0, stream>>>(x, meang, qh, (int)(GE / 4));
    cvt_k<<<(Cdim * Cdim / 4) / 256, 256, 0, stream>>>(Wq, nullptr, wqh, Cdim * Cdim / 4);
    cvt_k<<<(Cdim * Cdim / 4) / 256, 256, 0, stream>>>(Wg, nullptr, wgh, Cdim * Cdim / 4);

    // 2b. gT: per 192-block transpose  [NBLK][512][192]
    transpose1<<<dim3(Cdim / 64, BLK / 64, NBLK), 256, 0, stream>>>(
        gh, gTh, BLK, Cdim, (long)BLK * Cdim, (long)Cdim * BLK);

    // 3. rel_q = q @ Wq^T -> f16  [15360,512]  (960 blocks)
    mfma_gemm<2, 4><<<dim3(Cdim / 128, Mrows / 64), 256, 0, stream>>>(
        qh, wqh, nullptr, rqh, Cdim, Cdim, Cdim, 0, 0, 0, 1.0f, nullptr, nullptr, 0);

    // 4. block scores = (g·g^T)*invn_i*invn_j*SCALE -> f16  [80][192][192]  (720 blocks)
    mfma_gemm<2, 2><<<dim3(3, 3, NBLK), 256, 0, stream>>>(
        gh, gh, nullptr, sbh, BLK, Cdim, Cdim,
        (long)BLK * Cdim, (long)BLK * Cdim, (long)BLK * BLK,
        SCALE, invn, invn, BLK);

    // 5. block softmax in place
    softmax_h<<<NBLK * BLK, 256, 0, stream>>>(sbh, BLK);

    // 6. g2 = attn · (gT)^T -> f16  [80][192][512]  (960 blocks)
    mfma_gemm<2, 4><<<dim3(Cdim / 128, BLK / 64, NBLK), 256, 0, stream>>>(
        sbh, gTh, nullptr, g2h, Cdim, BLK, BLK,
        (long)BLK * BLK, (long)Cdim * BLK, (long)BLK * Cdim,
        1.0f, nullptr, nullptr, 0);

    // 6b. g2T: per-batch transpose  [Bsz][512][1920]  (into dead q buffer)
    transpose1<<<dim3(Cdim / 64, Ntok / 64, Bsz), 256, 0, stream>>>(
        g2h, g2Th, Ntok, Cdim, (long)Ntok * Cdim, (long)Cdim * Ntok);

    // 7. rel_g = g2 @ Wg^T -> f16  [15360,512]  (960 blocks)
    mfma_gemm<2, 4><<<dim3(Cdim / 128, Mrows / 64), 256, 0, stream>>>(
        g2h, wgh, nullptr, rgh, Cdim, Cdim, Cdim, 0, 0, 0, 1.0f, nullptr, nullptr, 0);

    // 8. global scores = rel_q @ rel_g^T * SCALE -> f16  [8][1920][1920]  (1800 blocks)
    mfma_gemm<4, 4><<<dim3(Ntok / 128, Ntok / 128, Bsz), 256, 0, stream>>>(
        rqh, rgh, nullptr, s2h, Ntok, Cdim, Cdim,
        (long)Ntok * Cdim, (long)Ntok * Cdim, (long)Ntok * Ntok,
        SCALE, nullptr, nullptr, 0);

    // 9. global softmax in place  (15360 rows of 1920)
    softmax_h<<<Bsz * Ntok, 256, 0, stream>>>(s2h, Ntok);

    // 10. out = attn2 · (g2T)^T -> f32  [8][1920][512]  (960 blocks)
    mfma_gemm<2, 4><<<dim3(Cdim / 128, Ntok / 64, Bsz), 256, 0, stream>>>(
        s2h, g2Th, out, nullptr, Cdim, Ntok, Ntok,
        (long)Ntok * Ntok, (long)Cdim * Ntok, (long)Ntok * Cdim,
        1.0f, nullptr, nullptr, 0);
}

// Round 8
// 285.705 us; speedup vs baseline: 3.5614x; 1.0664x over previous
//
#include <hip/hip_runtime.h>
#include <math.h>

// Problem constants
constexpr int Bsz  = 8;
constexpr int Ntok = 1920;
constexpr int Cdim = 512;
constexpr int BLK  = 192;
constexpr int Mrows = Bsz * Ntok;      // 15360
constexpr int NBLK  = Mrows / BLK;     // 80
constexpr float SCALE = 0.02209708691207961f;  // 2048^-0.5

typedef _Float16 half8 __attribute__((ext_vector_type(8)));
typedef float    f32x4 __attribute__((ext_vector_type(4)));

#define GLOAD_LDS16(gp, lp) __builtin_amdgcn_global_load_lds( \
    (const __attribute__((address_space(1))) void*)(gp),      \
    (__attribute__((address_space(3))) void*)(lp), 16, 0, 0)

// chunk swizzle within a 64B row (4 x 16B chunks): applied on BOTH the global
// source chunk (staging) and the ds_read chunk -> involution, banks spread.
__device__ inline int sfun(int r) { return (r & 3) ^ ((r >> 2) & 3); }

// ---- f16 helpers ----
__device__ inline unsigned short f2h(float f) {
    _Float16 h = (_Float16)f;
    return __builtin_bit_cast(unsigned short, h);
}
__device__ inline float h2f(unsigned short u) {
    return (float)__builtin_bit_cast(_Float16, u);
}

// ---------------- token mean (two-stage) ----------------
__global__ void mean_partial(const float* __restrict__ g, float* __restrict__ part) {
    int b = blockIdx.x, t = blockIdx.y, c = threadIdx.x;
    const float* p = g + ((size_t)b * Ntok + (size_t)t * 48) * Cdim + c;
    float s = 0.f;
    #pragma unroll 4
    for (int n = 0; n < 48; ++n) s += p[(size_t)n * Cdim];
    part[((size_t)b * 40 + t) * Cdim + c] = s;
}

__global__ void mean_final(const float* __restrict__ part, float* __restrict__ meang) {
    int b = blockIdx.x, c = threadIdx.x;
    float s = 0.f;
    for (int t = 0; t < 40; ++t) s += part[((size_t)b * 40 + t) * Cdim + c];
    meang[b * Cdim + c] = s * (1.0f / (float)Ntok);
}

// ---------------- per-row inverse norm of g (f32 source) ----------------
__global__ void invnorm_k(const float* __restrict__ g, float* __restrict__ invn) {
    int wid = threadIdx.x >> 6, lane = threadIdx.x & 63;
    int row = blockIdx.x * 4 + wid;
    const float* p = g + (size_t)row * Cdim;
    float ss = 0.f;
    #pragma unroll
    for (int i = lane; i < Cdim; i += 64) { float v = p[i]; ss += v * v; }
    #pragma unroll
    for (int o = 1; o < 64; o <<= 1) ss += __shfl_xor(ss, o);
    if (lane == 0) {
        float n = sqrtf(ss);
        invn[row] = 1.0f / fmaxf(n, 1e-12f);
    }
}

// ---------------- f32 -> f16 convert, optional per-token bias ----------------
__global__ void cvt_k(const float* __restrict__ src, const float* __restrict__ bias,
                      unsigned short* __restrict__ dst, int n4) {
    int i = blockIdx.x * 256 + threadIdx.x;
    if (i >= n4) return;
    float4 v = ((const float4*)src)[i];
    if (bias) {
        int b  = i / (Ntok * Cdim / 4);
        int c4 = (i & (Cdim / 4 - 1)) << 2;
        float4 bv = *(const float4*)&bias[b * Cdim + c4];
        v.x += bv.x; v.y += bv.y; v.z += bv.z; v.w += bv.w;
    }
    ushort4 h;
    h.x = f2h(v.x); h.y = f2h(v.y); h.z = f2h(v.z); h.w = f2h(v.w);
    ((ushort4*)dst)[i] = h;
}

// ---------------- batched 64x64-tiled u16 transpose ----------------
__global__ __launch_bounds__(256) void transpose1(
    const unsigned short* __restrict__ in, unsigned short* __restrict__ out,
    int R, int C, long inB, long outB)
{
    int z = blockIdx.z;
    in  += (size_t)z * inB;
    out += (size_t)z * outB;
    __shared__ unsigned short th[64][68];
    int r0 = blockIdx.y * 64, c0 = blockIdx.x * 64;
    int tr = threadIdx.x >> 4, tc = (threadIdx.x & 15) * 4;
    for (int rr = tr; rr < 64; rr += 16) {
        ushort4 h = *(const ushort4*)&in[(size_t)(r0 + rr) * C + c0 + tc];
        th[tc + 0][rr] = h.x; th[tc + 1][rr] = h.y; th[tc + 2][rr] = h.z; th[tc + 3][rr] = h.w;
    }
    __syncthreads();
    for (int cc = tr; cc < 64; cc += 16) {
        ushort4 h = *(const ushort4*)&th[cc][tc];
        *(ushort4*)&out[(size_t)(c0 + cc) * R + r0 + tc] = h;
    }
}

// ---------------- f16 MFMA GEMM (NT), 2-phase dbuf pipeline + XCD swizzle ------
// O = alpha * rs*cs * (A · B^T); A [M,ld], B [N,ld] k-contiguous f16;
// f32 accumulate. Tile BM=FM*32 x BN=FN*32, 4 waves as 2x2. Batched over z.
// Pipeline: STAGE(next) || compute(cur); one barrier per K-step (T3-minimum).
template<int FM, int FN>
__global__ __launch_bounds__(256) void mfma_gemm(
    const unsigned short* __restrict__ A, const unsigned short* __restrict__ B,
    float* __restrict__ Of32, unsigned short* __restrict__ Oh,
    int N, int K, int ld,
    long aB, long bB, long oB,
    float alpha, const float* __restrict__ rs, const float* __restrict__ cs, int sB)
{
    constexpr int BM = FM * 32, BN = FN * 32;
    constexpr int NCH = (BM + BN) / 16;   // 1KB staging chunks per K-step
    constexpr int CPW = NCH / 4;          // chunks per wave
    int z = blockIdx.z;

    // bijective XCD-aware swizzle of the tile index within this z-slice (m204)
    int gx = gridDim.x;
    int nwg = gx * gridDim.y;
    int orig = blockIdx.y * gx + blockIdx.x;
    int q = nwg >> 3, r = nwg & 7;
    int xcd = orig & 7, idx = orig >> 3;
    int wgid = (xcd < r ? xcd * (q + 1) : r * (q + 1) + (xcd - r) * q) + idx;
    int m0 = (wgid / gx) * BM, n0 = (wgid % gx) * BN;

    __shared__ __align__(16) unsigned short As[2][BM * 32];
    __shared__ __align__(16) unsigned short Bs[2][BN * 32];

    int tid  = threadIdx.x;
    int lane = tid & 63, wid = tid >> 6;
    int wm = (wid >> 1) * (FM * 16), wn = (wid & 1) * (FN * 16);

    // staging: lane -> (row = lane>>2 within 16-row chunk, swizzled 16B slot)
    int srow = lane >> 2;
    int sgc  = (lane & 3) ^ sfun(srow);

    const unsigned short* csrc[CPW];
    unsigned short* cdst0[CPW];
    unsigned short* cdst1[CPW];
    #pragma unroll
    for (int i = 0; i < CPW; ++i) {
        int c = wid * CPW + i;                 // wave-uniform
        if (c < BM / 16) {
            csrc[i]  = A + (size_t)z * aB + (size_t)(m0 + c * 16 + srow) * ld + sgc * 8;
            cdst0[i] = &As[0][c * 512];
            cdst1[i] = &As[1][c * 512];
        } else {
            int cb = c - BM / 16;
            csrc[i]  = B + (size_t)z * bB + (size_t)(n0 + cb * 16 + srow) * ld + sgc * 8;
            cdst0[i] = &Bs[0][cb * 512];
            cdst1[i] = &Bs[1][cb * 512];
        }
    }

    f32x4 acc[FM][FN] = {};
    int fr = lane & 15, kg = lane >> 4;

    const int nt = K / 32;
    // prologue: stage tile 0 into buffer 0
    #pragma unroll
    for (int i = 0; i < CPW; ++i) GLOAD_LDS16(csrc[i], cdst0[i]);
    __syncthreads();

    for (int t = 0; t < nt; ++t) {
        int cur = t & 1;
        // issue next tile's loads into the other buffer (stay in flight
        // across the compute; drained by the barrier's vmcnt at loop end)
        if (t + 1 < nt) {
            const int k1 = (t + 1) * 32;
            #pragma unroll
            for (int i = 0; i < CPW; ++i)
                GLOAD_LDS16(csrc[i] + k1, cur ? cdst0[i] : cdst1[i]);
        }
        // compute current tile
        const unsigned short* Ab = As[cur];
        const unsigned short* Bb = Bs[cur];
        half8 a[FM], b[FN];
        #pragma unroll
        for (int f = 0; f < FM; ++f) {
            int rr = wm + f * 16 + fr;
            a[f] = *(const half8*)&Ab[rr * 32 + ((kg ^ sfun(rr)) << 3)];
        }
        #pragma unroll
        for (int f = 0; f < FN; ++f) {
            int rr = wn + f * 16 + fr;
            b[f] = *(const half8*)&Bb[rr * 32 + ((kg ^ sfun(rr)) << 3)];
        }
        #pragma unroll
        for (int i = 0; i < FM; ++i)
            #pragma unroll
            for (int j = 0; j < FN; ++j)
                acc[i][j] = __builtin_amdgcn_mfma_f32_16x16x32_f16(a[i], b[j], acc[i][j], 0, 0, 0);
        __syncthreads();
    }

    float* O          = Of32 ? Of32 + (size_t)z * oB : nullptr;
    unsigned short* H = Oh   ? Oh   + (size_t)z * oB : nullptr;
    int fq = lane >> 4;
    #pragma unroll
    for (int i = 0; i < FM; ++i) {
        #pragma unroll
        for (int r4 = 0; r4 < 4; ++r4) {
            int gm = m0 + wm + i * 16 + fq * 4 + r4;
            float rf = alpha * (rs ? rs[(size_t)z * sB + gm] : 1.0f);
            #pragma unroll
            for (int j = 0; j < FN; ++j) {
                int gn = n0 + wn + j * 16 + fr;
                float v = acc[i][j][r4] * rf * (cs ? cs[(size_t)z * sB + gn] : 1.0f);
                size_t off = (size_t)gm * N + gn;
                if (O) O[off] = v;
                else   H[off] = f2h(v);
            }
        }
    }
}

// ---------------- in-place row softmax on f16 scores ----------------
__global__ __launch_bounds__(256) void softmax_h(unsigned short* __restrict__ P, int cols) {
    __shared__ float buf[1920];
    __shared__ float red[4];
    size_t row = blockIdx.x;
    unsigned short* p = P + row * (size_t)cols;
    int tid = threadIdx.x;
    int nq = cols >> 2;

    float lmax = -1e30f;
    for (int q = tid; q < nq; q += 256) {
        ushort4 h = ((const ushort4*)p)[q];
        float v0 = h2f(h.x), v1 = h2f(h.y), v2 = h2f(h.z), v3 = h2f(h.w);
        buf[q * 4 + 0] = v0; buf[q * 4 + 1] = v1;
        buf[q * 4 + 2] = v2; buf[q * 4 + 3] = v3;
        lmax = fmaxf(lmax, fmaxf(fmaxf(v0, v1), fmaxf(v2, v3)));
    }
    #pragma unroll
    for (int o = 1; o < 64; o <<= 1) lmax = fmaxf(lmax, __shfl_xor(lmax, o));
    if ((tid & 63) == 0) red[tid >> 6] = lmax;
    __syncthreads();
    float bmax = fmaxf(fmaxf(red[0], red[1]), fmaxf(red[2], red[3]));

    float lsum = 0.f;
    for (int c = tid; c < cols; c += 256) {
        float e = expf(buf[c] - bmax);
        buf[c] = e;
        lsum += e;
    }
    #pragma unroll
    for (int o = 1; o < 64; o <<= 1) lsum += __shfl_xor(lsum, o);
    __syncthreads();
    if ((tid & 63) == 0) red[tid >> 6] = lsum;
    __syncthreads();
    float inv = 1.0f / (red[0] + red[1] + red[2] + red[3]);

    for (int q = tid; q < nq; q += 256) {
        ushort4 h;
        h.x = f2h(buf[q * 4 + 0] * inv);
        h.y = f2h(buf[q * 4 + 1] * inv);
        h.z = f2h(buf[q * 4 + 2] * inv);
        h.w = f2h(buf[q * 4 + 3] * inv);
        ((ushort4*)p)[q] = h;
    }
}

// ---------------- launch ----------------
extern "C" void kernel_launch(void* const* d_in, const int* in_sizes, int n_in,
                              void* d_out, int out_size, void* d_ws, size_t ws_size,
                              hipStream_t stream) {
    (void)in_sizes; (void)n_in; (void)out_size; (void)ws_size;
    const float* x  = (const float*)d_in[0];
    const float* g  = (const float*)d_in[1];
    const float* Wq = (const float*)d_in[2];
    const float* Wg = (const float*)d_in[3];
    float* out = (float*)d_out;

    const size_t GE = (size_t)Mrows * Cdim;      // 7,864,320 elems
    char* ws = (char*)d_ws;
    size_t off = 0;
    auto alloc = [&](size_t bytes) { char* p = ws + off; off += (bytes + 255) & ~(size_t)255; return p; };

    float* meang = (float*)alloc(Bsz * Cdim * 4);
    float* part  = (float*)alloc(Bsz * 40 * Cdim * 4);
    float* invn  = (float*)alloc(Mrows * 4);
    unsigned short* gh   = (unsigned short*)alloc(GE * 2);            // g f16
    unsigned short* gTh  = (unsigned short*)alloc(GE * 2);            // [NBLK][512][192]
    unsigned short* qh   = (unsigned short*)alloc(GE * 2);            // q f16; reused as g2T
    unsigned short* wqh  = (unsigned short*)alloc((size_t)Cdim * Cdim * 2);
    unsigned short* wgh  = (unsigned short*)alloc((size_t)Cdim * Cdim * 2);
    unsigned short* rqh  = (unsigned short*)alloc(GE * 2);
    unsigned short* rgh  = (unsigned short*)alloc(GE * 2);
    unsigned short* g2h  = (unsigned short*)alloc(GE * 2);
    unsigned short* sbh  = (unsigned short*)alloc((size_t)NBLK * BLK * BLK * 2);
    unsigned short* s2h  = (unsigned short*)alloc((size_t)Bsz * Ntok * Ntok * 2);  // 59 MB
    unsigned short* g2Th = qh;                                        // [Bsz][512][1920]

    // 1. token mean; per-row inv norms (f32 sources)
    mean_partial<<<dim3(Bsz, 40), 512, 0, stream>>>(g, part);
    mean_final<<<Bsz, 512, 0, stream>>>(part, meang);
    invnorm_k<<<Mrows / 4, 256, 0, stream>>>(g, invn);

    // 2. f16 conversions
    cvt_k<<<(int)(GE / 4 + 255) / 256, 256, 0, stream>>>(g, nullptr, gh, (int)(GE / 4));
    cvt_k<<<(int)(GE / 4 + 255) / 256, 256, 0, stream>>>(x, meang, qh, (int)(GE / 4));
    cvt_k<<<(Cdim * Cdim / 4) / 256, 256, 0, stream>>>(Wq, nullptr, wqh, Cdim * Cdim / 4);
    cvt_k<<<(Cdim * Cdim / 4) / 256, 256, 0, stream>>>(Wg, nullptr, wgh, Cdim * Cdim / 4);

    // 2b. gT: per 192-block transpose  [NBLK][512][192]
    transpose1<<<dim3(Cdim / 64, BLK / 64, NBLK), 256, 0, stream>>>(
        gh, gTh, BLK, Cdim, (long)BLK * Cdim, (long)Cdim * BLK);

    // 3. rel_q = q @ Wq^T -> f16  [15360,512]  (960 blocks)
    mfma_gemm<2, 4><<<dim3(Cdim / 128, Mrows / 64), 256, 0, stream>>>(
        qh, wqh, nullptr, rqh, Cdim, Cdim, Cdim, 0, 0, 0, 1.0f, nullptr, nullptr, 0);

    // 4. block scores = (g·g^T)*invn_i*invn_j*SCALE -> f16  [80][192][192]  (720 blocks)
    mfma_gemm<2, 2><<<dim3(3, 3, NBLK), 256, 0, stream>>>(
        gh, gh, nullptr, sbh, BLK, Cdim, Cdim,
        (long)BLK * Cdim, (long)BLK * Cdim, (long)BLK * BLK,
        SCALE, invn, invn, BLK);

    // 5. block softmax in place
    softmax_h<<<NBLK * BLK, 256, 0, stream>>>(sbh, BLK);

    // 6. g2 = attn · (gT)^T -> f16  [80][192][512]  (960 blocks)
    mfma_gemm<2, 4><<<dim3(Cdim / 128, BLK / 64, NBLK), 256, 0, stream>>>(
        sbh, gTh, nullptr, g2h, Cdim, BLK, BLK,
        (long)BLK * BLK, (long)Cdim * BLK, (long)BLK * Cdim,
        1.0f, nullptr, nullptr, 0);

    // 6b. g2T: per-batch transpose  [Bsz][512][1920]  (into dead q buffer)
    transpose1<<<dim3(Cdim / 64, Ntok / 64, Bsz), 256, 0, stream>>>(
        g2h, g2Th, Ntok, Cdim, (long)Ntok * Cdim, (long)Cdim * Ntok);

    // 7. rel_g = g2 @ Wg^T -> f16  [15360,512]  (960 blocks)
    mfma_gemm<2, 4><<<dim3(Cdim / 128, Mrows / 64), 256, 0, stream>>>(
        g2h, wgh, nullptr, rgh, Cdim, Cdim, Cdim, 0, 0, 0, 1.0f, nullptr, nullptr, 0);

    // 8. global scores = rel_q @ rel_g^T * SCALE -> f16  [8][1920][1920]  (1800 blocks)
    mfma_gemm<4, 4><<<dim3(Ntok / 128, Ntok / 128, Bsz), 256, 0, stream>>>(
        rqh, rgh, nullptr, s2h, Ntok, Cdim, Cdim,
        (long)Ntok * Cdim, (long)Ntok * Cdim, (long)Ntok * Ntok,
        SCALE, nullptr, nullptr, 0);

    // 9. global softmax in place  (15360 rows of 1920)
    softmax_h<<<Bsz * Ntok, 256, 0, stream>>>(s2h, Ntok);

    // 10. out = attn2 · (g2T)^T -> f32  [8][1920][512]  (960 blocks)
    mfma_gemm<2, 4><<<dim3(Cdim / 128, Ntok / 64, Bsz), 256, 0, stream>>>(
        s2h, g2Th, out, nullptr, Cdim, Ntok, Ntok,
        (long)Ntok * Ntok, (long)Cdim * Ntok, (long)Ntok * Cdim,
        1.0f, nullptr, nullptr, 0);
}